// Round 2
// baseline (103.890 us; speedup 1.0000x reference)
//
#include <hip/hip_runtime.h>

// PixelVectorExtractor: one transformer encoder layer over per-pixel 7x7
// windows embedded in a 30x30 canvas (S=900, D=11). Structural facts used:
//  - Only 49 of 900 sequence positions are nonzero; the other 851 rows are
//    exactly zero (PAD_VALUE=0, canvas fill=0).
//  - No biases => zero rows have q=k=v=0 exactly; all 851 zero rows of a
//    pixel share ONE encoder output vector (uniform softmax, denom=900).
//  - Window-row softmax: the 851 zero-score keys contribute 851*exp(-m) to
//    the denominator and nothing to the numerator (their v=0).
// Per pixel b: compute 49 real rows + 1 shared zero-row, then broadcast.
//
// Dtypes: reference setup_inputs() is float32 -> inputs are const float*,
// output is float*. (R1 NaN came from misreading fp32 buffers as bf16.)

#define D 11
#define NW 49       // nonzero (window) rows
#define NR 50       // 49 window rows + 1 shared zero-row
#define SEQ 900
#define FFD 64
#define CIN 10
#define NB 256      // N*H*W = 1*16*16
#define TPB 128

__device__ __forceinline__ void layernorm11(float* v, const float* w) {
    float m = 0.f;
    #pragma unroll
    for (int d = 0; d < D; ++d) m += v[d];
    m *= (1.0f / 11.0f);
    float var = 0.f;
    #pragma unroll
    for (int d = 0; d < D; ++d) { float t = v[d] - m; var += t * t; }
    var *= (1.0f / 11.0f);
    const float inv = rsqrtf(var + 1e-5f);
    #pragma unroll
    for (int d = 0; d < D; ++d) v[d] = (v[d] - m) * inv * w[d];
}

__global__ __launch_bounds__(TPB) void pve_kernel(
    const float* __restrict__ gx,     // [10,16,16]
    const float* __restrict__ gWqkv,  // [33,11]
    const float* __restrict__ gWo,    // [11,11]
    const float* __restrict__ gW1,    // [64,11]
    const float* __restrict__ gW2,    // [11,64]
    const float* __restrict__ gln1,   // [11]
    const float* __restrict__ gln2,   // [11]
    float* __restrict__ out)          // [256,10,900]
{
    __shared__ float sQ[33 * D];
    __shared__ float sWo[D * D];
    __shared__ float sW1[FFD * D];
    __shared__ float sW2[D * FFD];
    __shared__ float sln1[D], sln2[D];
    __shared__ float K[NW][D];
    __shared__ float V[NW][D];
    __shared__ float R[NR][D];   // encoder output rows; R[49] = shared zero-row

    const int tid = threadIdx.x;

    // stage weights to LDS
    for (int i = tid; i < 33 * D; i += TPB) sQ[i]  = gWqkv[i];
    for (int i = tid; i < D * D;  i += TPB) sWo[i] = gWo[i];
    for (int i = tid; i < FFD * D; i += TPB) sW1[i] = gW1[i];
    for (int i = tid; i < D * FFD; i += TPB) sW2[i] = gW2[i];
    if (tid < D) { sln1[tid] = gln1[tid]; sln2[tid] = gln2[tid]; }

    const int b = blockIdx.x;
    const int h = b >> 4;
    const int w = b & 15;
    const int r = tid;           // row id: 0..48 window rows, 49 zero-row

    // build this lane's input row (padded-image coords y,x in [0,22))
    float seq[D];
    float q[D];
    if (r < NR) {
        if (r < NW) {
            const int i = r / 7, j = r % 7;
            const int y = h + i, xx = w + j;
            const bool inter = (y >= 3) && (y < 19) && (xx >= 3) && (xx < 19);
            const int base = inter ? ((y - 3) * 16 + (xx - 3)) : 0;  // clamp: no OOB even if speculated
            #pragma unroll
            for (int d = 0; d < CIN; ++d)
                seq[d] = inter ? gx[d * 256 + base] : 0.0f;
            seq[CIN] = inter ? 0.0f : 1.0f;   // mask channel: 1 in border
        } else {
            #pragma unroll
            for (int d = 0; d < D; ++d) seq[d] = 0.0f;
        }
    }
    __syncthreads();   // weights staged

    // qkv projection; K,V of the 49 real rows go to LDS
    if (r < NR) {
        #pragma unroll
        for (int d = 0; d < D; ++d) {
            float aq = 0.f, ak = 0.f, av = 0.f;
            #pragma unroll
            for (int e = 0; e < D; ++e) {
                const float se = seq[e];
                aq += se * sQ[d * D + e];
                ak += se * sQ[(D + d) * D + e];
                av += se * sQ[(2 * D + d) * D + e];
            }
            q[d] = aq;
            if (r < NW) { K[r][d] = ak; V[r][d] = av; }
        }
    }
    __syncthreads();

    if (r < NR) {
        const float scale = rsqrtf(11.0f);
        // pass 1: running max (851 zero-score entries => m >= 0)
        float m = 0.0f;
        for (int t = 0; t < NW; ++t) {
            float s = 0.f;
            #pragma unroll
            for (int d = 0; d < D; ++d) s += q[d] * K[t][d];
            m = fmaxf(m, s * scale);
        }
        // pass 2: exp-sum + weighted V accumulation
        float denom = 851.0f * expf(0.0f - m);
        float num[D];
        #pragma unroll
        for (int d = 0; d < D; ++d) num[d] = 0.f;
        for (int t = 0; t < NW; ++t) {
            float s = 0.f;
            #pragma unroll
            for (int d = 0; d < D; ++d) s += q[d] * K[t][d];
            const float e = expf(s * scale - m);
            denom += e;
            #pragma unroll
            for (int d = 0; d < D; ++d) num[d] += e * V[t][d];
        }
        const float inv = 1.0f / denom;

        // out-proj + residual, LN1
        float x1[D];
        #pragma unroll
        for (int d = 0; d < D; ++d) {
            float acc = 0.f;
            #pragma unroll
            for (int e = 0; e < D; ++e) acc += num[e] * sWo[d * D + e];
            x1[d] = seq[d] + acc * inv;
        }
        layernorm11(x1, sln1);

        // FF (11 -> 64 relu -> 11) + residual, LN2
        float yv[D];
        #pragma unroll
        for (int d = 0; d < D; ++d) yv[d] = x1[d];
        for (int f = 0; f < FFD; ++f) {
            float acc = 0.f;
            #pragma unroll
            for (int d = 0; d < D; ++d) acc += x1[d] * sW1[f * D + d];
            acc = fmaxf(acc, 0.0f);
            #pragma unroll
            for (int d = 0; d < D; ++d) yv[d] += acc * sW2[d * FFD + f];
        }
        layernorm11(yv, sln2);

        #pragma unroll
        for (int d = 0; d < D; ++d) R[r][d] = yv[d];
    }
    __syncthreads();

    // write out[b, c, s]: window positions get their row, rest the zero-row
    float* ob = out + b * (CIN * SEQ);
    for (int c = 0; c < CIN; ++c) {
        const float zv = R[NW][c];
        for (int s = tid; s < SEQ; s += TPB) {
            const int i = s / 30;
            const int j = s - i * 30;
            const float val = (i < 7 && j < 7) ? R[i * 7 + j][c] : zv;
            ob[c * SEQ + s] = val;
        }
    }
}

extern "C" void kernel_launch(void* const* d_in, const int* in_sizes, int n_in,
                              void* d_out, int out_size, void* d_ws, size_t ws_size,
                              hipStream_t stream) {
    (void)in_sizes; (void)n_in; (void)out_size; (void)d_ws; (void)ws_size;
    const float* x    = (const float*)d_in[0];
    const float* Wqkv = (const float*)d_in[1];
    const float* Wo   = (const float*)d_in[2];
    const float* W1   = (const float*)d_in[3];
    const float* W2   = (const float*)d_in[4];
    const float* ln1  = (const float*)d_in[5];
    const float* ln2  = (const float*)d_in[6];
    pve_kernel<<<NB, TPB, 0, stream>>>(x, Wqkv, Wo, W1, W2, ln1, ln2,
                                       (float*)d_out);
}

// Round 3
// 94.182 us; speedup vs baseline: 1.1031x; 1.1031x over previous
//
#include <hip/hip_runtime.h>

// PixelVectorExtractor: one transformer encoder layer over per-pixel 7x7
// windows in a 30x30 canvas (S=900, D=11). Structure exploited:
//  - only 49/900 rows nonzero; 851 zero rows share ONE output vector
//    (no biases => q=k=v=0 exactly for zero rows; uniform softmax).
//  - zero-score keys contribute exp(0)=1 each to the softmax denominator and
//    nothing to the numerator => denom = 851 + sum_t exp(s_t), no max pass
//    needed (|s| <= ~1: weights are 0.1-scaled, x in [0,1]).
// R2 post-mortem: 41us was LDS-latency chains in ROLLED loops (VALUBusy 7%).
// Fix: full unroll (pipelined ~6-12cyc/read vs 120cyc serial), __expf,
// drop max pass, float4 epilogue with independent iterations.

#define D 11
#define NW 49
#define NR 50
#define SEQ 900
#define FFD 64
#define CIN 10
#define NB 256
#define TPB 256

__device__ __forceinline__ void layernorm11(float* v, const float* w) {
    float m = 0.f;
    #pragma unroll
    for (int d = 0; d < D; ++d) m += v[d];
    m *= (1.0f / 11.0f);
    float var = 0.f;
    #pragma unroll
    for (int d = 0; d < D; ++d) { float t = v[d] - m; var += t * t; }
    var *= (1.0f / 11.0f);
    const float inv = rsqrtf(var + 1e-5f);
    #pragma unroll
    for (int d = 0; d < D; ++d) v[d] = (v[d] - m) * inv * w[d];
}

__global__ __launch_bounds__(TPB) void pve_kernel(
    const float* __restrict__ gx,     // [10,16,16]
    const float* __restrict__ gWqkv,  // [33,11]
    const float* __restrict__ gWo,    // [11,11]
    const float* __restrict__ gW1,    // [64,11]
    const float* __restrict__ gW2,    // [11,64]
    const float* __restrict__ gln1,   // [11]
    const float* __restrict__ gln2,   // [11]
    float* __restrict__ out)          // [256,10,900]
{
    __shared__ float sQ[33 * D];
    __shared__ float sWo[D * D];
    __shared__ float sW1[FFD * D];
    __shared__ float sW2[D * FFD];
    __shared__ float sln1[D], sln2[D];
    __shared__ float K[NW][D];
    __shared__ float V[NW][D];
    __shared__ float R[NR][D];   // R[49] = shared zero-row output

    const int tid = threadIdx.x;

    // stage weights to LDS (all uniform-broadcast consumers below)
    for (int i = tid; i < 33 * D; i += TPB) sQ[i]  = gWqkv[i];
    for (int i = tid; i < D * D;  i += TPB) sWo[i] = gWo[i];
    for (int i = tid; i < FFD * D; i += TPB) sW1[i] = gW1[i];
    for (int i = tid; i < D * FFD; i += TPB) sW2[i] = gW2[i];
    if (tid < D) { sln1[tid] = gln1[tid]; sln2[tid] = gln2[tid]; }

    const int b = blockIdx.x;
    const int h = b >> 4;
    const int w = b & 15;
    const int r = tid;          // 0..48 window rows, 49 = zero row

    float seq[D];
    float q[D];
    if (r < NR) {
        if (r < NW) {
            const int i = r / 7, j = r % 7;
            const int y = h + i, xx = w + j;
            const bool inter = (y >= 3) && (y < 19) && (xx >= 3) && (xx < 19);
            const int base = inter ? ((y - 3) * 16 + (xx - 3)) : 0;
            #pragma unroll
            for (int d = 0; d < CIN; ++d)
                seq[d] = inter ? gx[d * 256 + base] : 0.0f;
            seq[CIN] = inter ? 0.0f : 1.0f;
        } else {
            #pragma unroll
            for (int d = 0; d < D; ++d) seq[d] = 0.0f;
        }
    }
    __syncthreads();   // weights staged

    // qkv projection; K,V rows of the 49 real rows -> LDS
    if (r < NR) {
        #pragma unroll
        for (int d = 0; d < D; ++d) {
            float aq = 0.f, ak = 0.f, av = 0.f;
            #pragma unroll
            for (int e = 0; e < D; ++e) {
                const float se = seq[e];
                aq += se * sQ[d * D + e];
                ak += se * sQ[(D + d) * D + e];
                av += se * sQ[(2 * D + d) * D + e];
            }
            q[d] = aq;
            if (r < NW) { K[r][d] = ak; V[r][d] = av; }
        }
    }
    __syncthreads();

    if (r < NR) {
        const float scale = rsqrtf(11.0f);
        // single pass, no max subtraction: 851 zero-score keys => +851
        float denom = 851.0f;
        float num[D];
        #pragma unroll
        for (int d = 0; d < D; ++d) num[d] = 0.f;
        #pragma unroll
        for (int t = 0; t < NW; ++t) {
            float s = 0.f;
            #pragma unroll
            for (int d = 0; d < D; ++d) s += q[d] * K[t][d];
            const float e = __expf(s * scale);
            denom += e;
            #pragma unroll
            for (int d = 0; d < D; ++d) num[d] += e * V[t][d];
        }
        const float inv = 1.0f / denom;

        // out-proj + residual, LN1
        float x1[D];
        #pragma unroll
        for (int d = 0; d < D; ++d) {
            float acc = 0.f;
            #pragma unroll
            for (int e = 0; e < D; ++e) acc += num[e] * sWo[d * D + e];
            x1[d] = seq[d] + acc * inv;
        }
        layernorm11(x1, sln1);

        // FF (11 -> 64 relu -> 11) + residual, LN2
        float yv[D];
        #pragma unroll
        for (int d = 0; d < D; ++d) yv[d] = x1[d];
        #pragma unroll
        for (int f = 0; f < FFD; ++f) {
            float acc = 0.f;
            #pragma unroll
            for (int d = 0; d < D; ++d) acc += x1[d] * sW1[f * D + d];
            acc = fmaxf(acc, 0.0f);
            #pragma unroll
            for (int d = 0; d < D; ++d) yv[d] += acc * sW2[d * FFD + f];
        }
        layernorm11(yv, sln2);

        #pragma unroll
        for (int d = 0; d < D; ++d) R[r][d] = yv[d];
    }
    __syncthreads();

    // epilogue: out[b, c, s] as float4 (9000 floats = 2250 float4 per block)
    float4* ob4 = (float4*)(out + b * (CIN * SEQ));
    #pragma unroll
    for (int k = 0; k < 9; ++k) {
        const int qi = tid + k * TPB;
        if (qi < 2250) {
            const int c  = qi / 225;           // 900/4 = 225 float4 per channel
            const int s0 = (qi - c * 225) * 4;
            float4 v4;
            float* pv = (float*)&v4;
            #pragma unroll
            for (int u = 0; u < 4; ++u) {
                const int s = s0 + u;
                const int i = s / 30;
                const int j = s - i * 30;
                pv[u] = (i < 7 && j < 7) ? R[i * 7 + j][c] : R[NW][c];
            }
            ob4[qi] = v4;
        }
    }
}

extern "C" void kernel_launch(void* const* d_in, const int* in_sizes, int n_in,
                              void* d_out, int out_size, void* d_ws, size_t ws_size,
                              hipStream_t stream) {
    (void)in_sizes; (void)n_in; (void)out_size; (void)d_ws; (void)ws_size;
    const float* x    = (const float*)d_in[0];
    const float* Wqkv = (const float*)d_in[1];
    const float* Wo   = (const float*)d_in[2];
    const float* W1   = (const float*)d_in[3];
    const float* W2   = (const float*)d_in[4];
    const float* ln1  = (const float*)d_in[5];
    const float* ln2  = (const float*)d_in[6];
    pve_kernel<<<NB, TPB, 0, stream>>>(x, Wqkv, Wo, W1, W2, ln1, ln2,
                                       (float*)d_out);
}

// Round 4
// 80.713 us; speedup vs baseline: 1.2872x; 1.1669x over previous
//
#include <hip/hip_runtime.h>

// PixelVectorExtractor: one transformer encoder layer over per-pixel 7x7
// windows in a 30x30 canvas (S=900, D=11). Structure exploited:
//  - only 49/900 rows nonzero; 851 zero rows share ONE output vector
//    (no biases => q=k=v=0 exactly; uniform softmax, denom=900).
//  - zero-score keys: +851 to softmax denominator, nothing to numerator.
//    denom = 851 + sum_t exp(s_t); no max pass (|s| small: 0.1-scaled W).
//
// R3 post-mortem: 31us because ALL compute sat on one 50-lane wave per block
// (3.3k FMA + 1.3k ds_read serial, giant unrolled once-through code, nothing
// to hide latency). This version is phase-parallel: thread=(r,d) over
// 50 rows x 11 dims (550 threads), TPB=576 (9 waves), every phase is
// <=~100 FMA/thread with LDS handoffs between phases.

#define D 11
#define NW 49
#define NR 50
#define SEQ 900
#define FFD 64
#define CIN 10
#define NB 256
#define TPB 576
#define NRD (NR * D)   // 550

__global__ __launch_bounds__(TPB) void pve_kernel(
    const float* __restrict__ gx,     // [10,16,16]
    const float* __restrict__ gWqkv,  // [33,11]
    const float* __restrict__ gWo,    // [11,11]
    const float* __restrict__ gW1,    // [64,11]
    const float* __restrict__ gW2,    // [11,64]
    const float* __restrict__ gln1,   // [11]
    const float* __restrict__ gln2,   // [11]
    float* __restrict__ out)          // [256,10,900]
{
    __shared__ float sQ[33 * D];      // Wqkv
    __shared__ float sWo[D * D];
    __shared__ float sW1[FFD * D];    // [f][d]
    __shared__ float sW2[D * FFD];    // [d][f]
    __shared__ float sln1[D], sln2[D];
    __shared__ float sSeq[NR][D];
    __shared__ float sK[NW][D];
    __shared__ float sV[NW][D];
    __shared__ float sQr[NR][D];
    __shared__ float sE[NR][NW];      // exp(scores)
    __shared__ float sNum[NR][D];
    __shared__ float sDen[NR];
    __shared__ float sX1[NR][D];      // raw after attn+residual
    __shared__ float sX1n[NR][D];     // after LN1
    __shared__ float sH[NR][FFD];     // FF hidden (relu)
    __shared__ float sY[NR][D];       // raw after FF+residual
    __shared__ float sR[NR][D];       // final rows (sR[49] = zero-row output)

    const int tid = threadIdx.x;
    const int b = blockIdx.x;
    const int h = b >> 4;
    const int w = b & 15;

    const int rd = tid;               // (r,d) flat id, valid when < 550
    const int r = rd / D;
    const int d = rd - r * D;

    // ---- phase 0: stage weights + build seq rows ----
    for (int i = tid; i < 33 * D; i += TPB) sQ[i]  = gWqkv[i];
    for (int i = tid; i < D * D;  i += TPB) sWo[i] = gWo[i];
    for (int i = tid; i < FFD * D; i += TPB) sW1[i] = gW1[i];
    for (int i = tid; i < D * FFD; i += TPB) sW2[i] = gW2[i];
    if (tid < D) { sln1[tid] = gln1[tid]; sln2[tid] = gln2[tid]; }

    if (rd < NRD) {
        float val = 0.0f;
        if (r < NW) {
            const int i = r / 7, j = r - (r / 7) * 7;
            const int y = h + i, xx = w + j;
            const bool inter = (y >= 3) && (y < 19) && (xx >= 3) && (xx < 19);
            const int base = inter ? ((y - 3) * 16 + (xx - 3)) : 0;
            if (d < CIN) val = inter ? gx[d * 256 + base] : 0.0f;
            else         val = inter ? 0.0f : 1.0f;     // mask channel
        }
        sSeq[r][d] = val;                               // r==49: zero row
    }
    __syncthreads();

    // ---- phase 1: qkv projection, thread=(r,d) ----
    if (rd < NRD) {
        float aq = 0.f, ak = 0.f, av = 0.f;
        #pragma unroll
        for (int e = 0; e < D; ++e) {
            const float se = sSeq[r][e];
            aq += se * sQ[d * D + e];
            ak += se * sQ[(D + d) * D + e];
            av += se * sQ[(2 * D + d) * D + e];
        }
        sQr[r][d] = aq;
        if (r < NW) { sK[r][d] = ak; sV[r][d] = av; }
    }
    __syncthreads();

    // ---- phase 2: scores + exp, 50x49 = 2450 over 576 threads ----
    {
        const float scale = rsqrtf(11.0f);
        #pragma unroll
        for (int k = 0; k < 5; ++k) {
            const int idx = tid + k * TPB;
            if (idx < NR * NW) {
                const int rr = idx / NW;
                const int tt = idx - rr * NW;
                float s = 0.f;
                #pragma unroll
                for (int e = 0; e < D; ++e) s += sQr[rr][e] * sK[tt][e];
                sE[rr][tt] = __expf(s * scale);
            }
        }
    }
    __syncthreads();

    // ---- phase 3: softmax numerator/denominator ----
    if (rd < NRD) {
        float acc = 0.f;
        #pragma unroll
        for (int t = 0; t < NW; ++t) acc += sE[r][t] * sV[t][d];
        sNum[r][d] = acc;
        if (d == 0) {
            float den = 851.0f;                  // 851 zero-score keys
            #pragma unroll
            for (int t = 0; t < NW; ++t) den += sE[r][t];
            sDen[r] = den;
        }
    }
    __syncthreads();

    // ---- phase 4: out-proj + residual ----
    if (rd < NRD) {
        float acc = 0.f;
        #pragma unroll
        for (int e = 0; e < D; ++e) acc += sNum[r][e] * sWo[d * D + e];
        sX1[r][d] = sSeq[r][d] + acc / sDen[r];
    }
    __syncthreads();

    // ---- phase 5: LN1 (redundant per-thread row stats) ----
    if (rd < NRD) {
        float row[D];
        #pragma unroll
        for (int e = 0; e < D; ++e) row[e] = sX1[r][e];
        float m = 0.f;
        #pragma unroll
        for (int e = 0; e < D; ++e) m += row[e];
        m *= (1.0f / 11.0f);
        float var = 0.f;
        #pragma unroll
        for (int e = 0; e < D; ++e) { float t = row[e] - m; var += t * t; }
        var *= (1.0f / 11.0f);
        sX1n[r][d] = (row[d] - m) * rsqrtf(var + 1e-5f) * sln1[d];
    }
    __syncthreads();

    // ---- phase 6: FF hidden, 50x64 = 3200 over 576 threads ----
    #pragma unroll
    for (int k = 0; k < 6; ++k) {
        const int idx = tid + k * TPB;
        if (idx < NR * FFD) {
            const int rr = idx >> 6;
            const int ff = idx & 63;
            float acc = 0.f;
            #pragma unroll
            for (int e = 0; e < D; ++e) acc += sX1n[rr][e] * sW1[ff * D + e];
            sH[rr][ff] = fmaxf(acc, 0.0f);
        }
    }
    __syncthreads();

    // ---- phase 7: FF out + residual ----
    if (rd < NRD) {
        float acc = 0.f;
        #pragma unroll
        for (int f = 0; f < FFD; ++f) acc += sH[r][f] * sW2[d * FFD + f];
        sY[r][d] = sX1n[r][d] + acc;
    }
    __syncthreads();

    // ---- phase 8: LN2 ----
    if (rd < NRD) {
        float row[D];
        #pragma unroll
        for (int e = 0; e < D; ++e) row[e] = sY[r][e];
        float m = 0.f;
        #pragma unroll
        for (int e = 0; e < D; ++e) m += row[e];
        m *= (1.0f / 11.0f);
        float var = 0.f;
        #pragma unroll
        for (int e = 0; e < D; ++e) { float t = row[e] - m; var += t * t; }
        var *= (1.0f / 11.0f);
        sR[r][d] = (row[d] - m) * rsqrtf(var + 1e-5f) * sln2[d];
    }
    __syncthreads();

    // ---- phase 9: epilogue, out[b,c,s] as float4 (2250 per block) ----
    float4* ob4 = (float4*)(out + b * (CIN * SEQ));
    #pragma unroll
    for (int k = 0; k < 4; ++k) {
        const int qi = tid + k * TPB;
        if (qi < 2250) {
            const int c  = qi / 225;             // 225 float4 per channel
            const int s0 = (qi - c * 225) * 4;
            float4 v4;
            float* pv = (float*)&v4;
            #pragma unroll
            for (int u = 0; u < 4; ++u) {
                const int s = s0 + u;
                const int i = s / 30;
                const int j = s - i * 30;
                pv[u] = (i < 7 && j < 7) ? sR[i * 7 + j][c] : sR[NW][c];
            }
            ob4[qi] = v4;
        }
    }
}

extern "C" void kernel_launch(void* const* d_in, const int* in_sizes, int n_in,
                              void* d_out, int out_size, void* d_ws, size_t ws_size,
                              hipStream_t stream) {
    (void)in_sizes; (void)n_in; (void)out_size; (void)d_ws; (void)ws_size;
    const float* x    = (const float*)d_in[0];
    const float* Wqkv = (const float*)d_in[1];
    const float* Wo   = (const float*)d_in[2];
    const float* W1   = (const float*)d_in[3];
    const float* W2   = (const float*)d_in[4];
    const float* ln1  = (const float*)d_in[5];
    const float* ln2  = (const float*)d_in[6];
    pve_kernel<<<NB, TPB, 0, stream>>>(x, Wqkv, Wo, W1, W2, ln1, ln2,
                                       (float*)d_out);
}

// Round 5
// 79.738 us; speedup vs baseline: 1.3029x; 1.0122x over previous
//
#include <hip/hip_runtime.h>

// PixelVectorExtractor: one transformer encoder layer over per-pixel 7x7
// windows in a 30x30 canvas (S=900, D=11). Structure exploited:
//  - only 49/900 rows nonzero; 851 zero rows share ONE output vector.
//  - zero-score keys: +851 to softmax denom, nothing to numerator.
// R4 post-mortem: 18us kernel was LDS-ISSUE-bound: ~580 scalar ds_read_b32
// per thread x 9 waves x ~5.8cyc on the per-CU LDS pipe ~= 30k cycles.
// v5: all hot LDS traffic is float4 (rows padded to 12 floats / E rows to 52,
// zero-padded so the extra lanes contribute 0 to dots), V stored transposed
// [d][t] so the softmax-numerator reduction is contiguous. ~150 b128/thread.

#define D 11
#define ROWP 12      // padded row length (3 x float4), pad element = 0
#define NW 49
#define NWP 52       // padded score-row length (13 x float4), pads = 0
#define NR 50
#define SEQ 900
#define FFD 64
#define CIN 10
#define NB 256
#define TPB 576
#define NRD (NR * D)  // 550

__device__ __forceinline__ float dot12(const float4* a, const float4* b) {
    float4 s = make_float4(0.f, 0.f, 0.f, 0.f);
    #pragma unroll
    for (int i = 0; i < 3; ++i) {
        float4 x = a[i], y = b[i];
        s.x += x.x * y.x; s.y += x.y * y.y; s.z += x.z * y.z; s.w += x.w * y.w;
    }
    return s.x + s.y + s.z + s.w;
}

__global__ __launch_bounds__(TPB) void pve_kernel(
    const float* __restrict__ gx,     // [10,16,16]
    const float* __restrict__ gWqkv,  // [33,11]
    const float* __restrict__ gWo,    // [11,11]
    const float* __restrict__ gW1,    // [64,11]
    const float* __restrict__ gW2,    // [11,64]
    const float* __restrict__ gln1,   // [11]
    const float* __restrict__ gln2,   // [11]
    float* __restrict__ out)          // [256,10,900]
{
    __shared__ __align__(16) float sQ[33 * ROWP];    // Wqkv rows, padded
    __shared__ __align__(16) float sWo[D * ROWP];
    __shared__ __align__(16) float sW1[FFD * ROWP];
    __shared__ __align__(16) float sW2[D * FFD];     // rows of 64, contiguous
    __shared__ float sln1[D], sln2[D];
    __shared__ __align__(16) float sSeq[NR][ROWP];
    __shared__ __align__(16) float sK[NW][ROWP];
    __shared__ __align__(16) float sVt[D][NWP];      // V transposed, [d][t]
    __shared__ __align__(16) float sQr[NR][ROWP];
    __shared__ __align__(16) float sE[NR][NWP];      // exp(scores), pads = 0
    __shared__ __align__(16) float sNum[NR][ROWP];
    __shared__ float sDen[NR];
    __shared__ __align__(16) float sX1[NR][ROWP];
    __shared__ __align__(16) float sX1n[NR][ROWP];
    __shared__ __align__(16) float sH[NR][FFD];
    __shared__ __align__(16) float sY[NR][ROWP];
    __shared__ __align__(16) float sR[NR][ROWP];

    const int tid = threadIdx.x;
    const int b = blockIdx.x;
    const int h = b >> 4;
    const int w = b & 15;

    const int rd = tid;               // (r,d), valid when < 550
    const int r = rd / D;
    const int d = rd - r * D;

    // ---- phase 0: stage weights (zero-padded rows) + build seq rows ----
    for (int i = tid; i < 33 * ROWP; i += TPB) {
        const int rr = i / ROWP, cc = i - rr * ROWP;
        sQ[i] = (cc < D) ? gWqkv[rr * D + cc] : 0.f;
    }
    for (int i = tid; i < D * ROWP; i += TPB) {
        const int rr = i / ROWP, cc = i - rr * ROWP;
        sWo[i] = (cc < D) ? gWo[rr * D + cc] : 0.f;
    }
    for (int i = tid; i < FFD * ROWP; i += TPB) {
        const int rr = i / ROWP, cc = i - rr * ROWP;
        sW1[i] = (cc < D) ? gW1[rr * D + cc] : 0.f;
    }
    for (int i = tid; i < D * FFD; i += TPB) sW2[i] = gW2[i];
    if (tid < D) { sln1[tid] = gln1[tid]; sln2[tid] = gln2[tid]; }

    if (rd < NRD) {
        float val = 0.0f;
        if (r < NW) {
            const int i = r / 7, j = r - (r / 7) * 7;
            const int y = h + i, xx = w + j;
            const bool inter = (y >= 3) && (y < 19) && (xx >= 3) && (xx < 19);
            const int base = inter ? ((y - 3) * 16 + (xx - 3)) : 0;
            if (d < CIN) val = inter ? gx[d * 256 + base] : 0.0f;
            else         val = inter ? 0.0f : 1.0f;     // mask channel
        }
        sSeq[r][d] = val;
        if (d == CIN) sSeq[r][D] = 0.f;                 // row pad
    }
    __syncthreads();

    // ---- phase 1: qkv projection, thread=(r,d); V written transposed ----
    if (rd < NRD) {
        const float4* sv = (const float4*)&sSeq[r][0];
        const float aq = dot12(sv, (const float4*)&sQ[d * ROWP]);
        const float ak = dot12(sv, (const float4*)&sQ[(D + d) * ROWP]);
        const float av = dot12(sv, (const float4*)&sQ[(2 * D + d) * ROWP]);
        sQr[r][d] = aq;
        if (d == CIN) sQr[r][D] = 0.f;
        if (r < NW) { sK[r][d] = ak; sVt[d][r] = av;
                      if (d == CIN) sK[r][D] = 0.f; }
        else { sVt[d][NW] = 0.f; sVt[d][NW + 1] = 0.f; sVt[d][NW + 2] = 0.f; }
    }
    __syncthreads();

    // ---- phase 2: scores + exp over padded 50x52 grid ----
    {
        const float scale = 0.30151134457776363f;   // 1/sqrt(11)
        #pragma unroll
        for (int k = 0; k < 5; ++k) {
            const int idx = tid + k * TPB;
            if (idx < NR * NWP) {
                const int rr = idx / NWP;
                const int tt = idx - rr * NWP;
                float e = 0.f;
                if (tt < NW) {
                    const float s = dot12((const float4*)&sQr[rr][0],
                                          (const float4*)&sK[tt][0]);
                    e = __expf(s * scale);
                }
                sE[rr][tt] = e;                     // pads get exactly 0
            }
        }
    }
    __syncthreads();

    // ---- phase 3: softmax numerator (and denom on d==0 lanes) ----
    if (rd < NRD) {
        const float4* ev = (const float4*)&sE[r][0];
        const float4* vv = (const float4*)&sVt[d][0];
        float4 an = make_float4(0.f, 0.f, 0.f, 0.f);
        float4 ad = make_float4(0.f, 0.f, 0.f, 0.f);
        #pragma unroll
        for (int i = 0; i < 13; ++i) {
            const float4 e = ev[i], v = vv[i];
            an.x += e.x * v.x; an.y += e.y * v.y;
            an.z += e.z * v.z; an.w += e.w * v.w;
            ad.x += e.x; ad.y += e.y; ad.z += e.z; ad.w += e.w;
        }
        sNum[r][d] = an.x + an.y + an.z + an.w;
        if (d == CIN) sNum[r][D] = 0.f;
        if (d == 0) sDen[r] = 851.0f + ad.x + ad.y + ad.z + ad.w;
    }
    __syncthreads();

    // ---- phase 4: out-proj + residual ----
    if (rd < NRD) {
        const float acc = dot12((const float4*)&sNum[r][0],
                                (const float4*)&sWo[d * ROWP]);
        sX1[r][d] = sSeq[r][d] + acc / sDen[r];
        if (d == CIN) sX1[r][D] = 0.f;
    }
    __syncthreads();

    // ---- phase 5: LN1 (pad element 0 contributes m^2 to raw var sum) ----
    if (rd < NRD) {
        const float4* xv = (const float4*)&sX1[r][0];
        float4 s4 = make_float4(0.f, 0.f, 0.f, 0.f);
        float4 q4 = make_float4(0.f, 0.f, 0.f, 0.f);
        #pragma unroll
        for (int i = 0; i < 3; ++i) {
            const float4 x = xv[i];
            s4.x += x.x; s4.y += x.y; s4.z += x.z; s4.w += x.w;
            q4.x += x.x * x.x; q4.y += x.y * x.y;
            q4.z += x.z * x.z; q4.w += x.w * x.w;
        }
        const float sum = s4.x + s4.y + s4.z + s4.w;
        const float sq  = q4.x + q4.y + q4.z + q4.w;
        const float m   = sum * (1.0f / 11.0f);
        const float var = sq * (1.0f / 11.0f) - m * m;   // pads are 0
        sX1n[r][d] = (sX1[r][d] - m) * rsqrtf(var + 1e-5f) * sln1[d];
        if (d == CIN) sX1n[r][D] = 0.f;
    }
    __syncthreads();

    // ---- phase 6: FF hidden, 50x64 over 576 threads ----
    #pragma unroll
    for (int k = 0; k < 6; ++k) {
        const int idx = tid + k * TPB;
        if (idx < NR * FFD) {
            const int rr = idx >> 6;
            const int ff = idx & 63;
            const float acc = dot12((const float4*)&sX1n[rr][0],
                                    (const float4*)&sW1[ff * ROWP]);
            sH[rr][ff] = fmaxf(acc, 0.0f);
        }
    }
    __syncthreads();

    // ---- phase 7: FF out + residual (contiguous over f) ----
    if (rd < NRD) {
        const float4* hv = (const float4*)&sH[r][0];
        const float4* wv = (const float4*)&sW2[d * FFD];
        float4 a4 = make_float4(0.f, 0.f, 0.f, 0.f);
        #pragma unroll
        for (int i = 0; i < 16; ++i) {
            const float4 hh = hv[i], ww = wv[i];
            a4.x += hh.x * ww.x; a4.y += hh.y * ww.y;
            a4.z += hh.z * ww.z; a4.w += hh.w * ww.w;
        }
        sY[r][d] = sX1n[r][d] + a4.x + a4.y + a4.z + a4.w;
        if (d == CIN) sY[r][D] = 0.f;
    }
    __syncthreads();

    // ---- phase 8: LN2 ----
    if (rd < NRD) {
        const float4* yv = (const float4*)&sY[r][0];
        float4 s4 = make_float4(0.f, 0.f, 0.f, 0.f);
        float4 q4 = make_float4(0.f, 0.f, 0.f, 0.f);
        #pragma unroll
        for (int i = 0; i < 3; ++i) {
            const float4 y = yv[i];
            s4.x += y.x; s4.y += y.y; s4.z += y.z; s4.w += y.w;
            q4.x += y.x * y.x; q4.y += y.y * y.y;
            q4.z += y.z * y.z; q4.w += y.w * y.w;
        }
        const float sum = s4.x + s4.y + s4.z + s4.w;
        const float sq  = q4.x + q4.y + q4.z + q4.w;
        const float m   = sum * (1.0f / 11.0f);
        const float var = sq * (1.0f / 11.0f) - m * m;
        sR[r][d] = (sY[r][d] - m) * rsqrtf(var + 1e-5f) * sln2[d];
    }
    __syncthreads();

    // ---- phase 9: epilogue, out[b,c,s] as float4 (2250 per block) ----
    float4* ob4 = (float4*)(out + b * (CIN * SEQ));
    #pragma unroll
    for (int k = 0; k < 4; ++k) {
        const int qi = tid + k * TPB;
        if (qi < 2250) {
            const int c  = qi / 225;             // 225 float4 per channel
            const int s0 = (qi - c * 225) * 4;
            float4 v4;
            float* pv = (float*)&v4;
            #pragma unroll
            for (int u = 0; u < 4; ++u) {
                const int s = s0 + u;
                const int i = s / 30;
                const int j = s - i * 30;
                pv[u] = (i < 7 && j < 7) ? sR[i * 7 + j][c] : sR[NW][c];
            }
            ob4[qi] = v4;
        }
    }
}

extern "C" void kernel_launch(void* const* d_in, const int* in_sizes, int n_in,
                              void* d_out, int out_size, void* d_ws, size_t ws_size,
                              hipStream_t stream) {
    (void)in_sizes; (void)n_in; (void)out_size; (void)d_ws; (void)ws_size;
    const float* x    = (const float*)d_in[0];
    const float* Wqkv = (const float*)d_in[1];
    const float* Wo   = (const float*)d_in[2];
    const float* W1   = (const float*)d_in[3];
    const float* W2   = (const float*)d_in[4];
    const float* ln1  = (const float*)d_in[5];
    const float* ln2  = (const float*)d_in[6];
    pve_kernel<<<NB, TPB, 0, stream>>>(x, Wqkv, Wo, W1, W2, ln1, ln2,
                                       (float*)d_out);
}